// Round 7
// baseline (457.540 us; speedup 1.0000x reference)
//
#include <hip/hip_runtime.h>
#include <hip/hip_bf16.h>
#include <cstdint>

// Problem shape (fixed by setup_inputs)
#define B_DIM 16384
#define U_DIM 512
#define K_DIM 1536   // 3U
#define N_DIM 2560   // 5U
#define NT    24     // K-tiles (K_DIM / 64)

typedef unsigned short u16;
typedef __attribute__((ext_vector_type(4))) unsigned short u16x4;
typedef __attribute__((ext_vector_type(8))) unsigned short u16x8;
typedef __attribute__((ext_vector_type(8))) short bf16x8;   // MFMA A/B frag (4 VGPR)
typedef __attribute__((ext_vector_type(4))) float f32x4;    // MFMA C/D frag

__device__ __forceinline__ u16 f2bf(float f) {
    uint32_t u = __builtin_bit_cast(uint32_t, f);
    u += 0x7FFFu + ((u >> 16) & 1u);   // round-to-nearest-even
    return (u16)(u >> 16);
}
__device__ __forceinline__ float bf2f(u16 h) {
    uint32_t u = ((uint32_t)h) << 16;
    return __builtin_bit_cast(float, u);
}

// ---------------------------------------------------------------------------
// Kernel 1: pack x = concat([inputs, h1, h2], axis=1) -> bf16 [B][3U]
// ---------------------------------------------------------------------------
__global__ void __launch_bounds__(256) cvt_x_kernel(
    const float* __restrict__ inp, const float* __restrict__ h1,
    const float* __restrict__ h2, u16* __restrict__ xb)
{
    int idx = blockIdx.x * 256 + threadIdx.x;       // one float4 per thread
    const int total4 = B_DIM * K_DIM / 4;
    if (idx >= total4) return;
    int e = idx * 4;
    int b = e / K_DIM;
    int k = e - b * K_DIM;
    const float* src;
    if (k < 512)       src = inp + b * 512 + k;
    else if (k < 1024) src = h1  + b * 512 + (k - 512);
    else               src = h2  + b * 512 + (k - 1024);
    float4 v = *(const float4*)src;
    u16x4 o;
    o.x = f2bf(v.x); o.y = f2bf(v.y); o.z = f2bf(v.z); o.w = f2bf(v.w);
    *(u16x4*)(xb + e) = o;
}

// ---------------------------------------------------------------------------
// Kernel 2: wT[n][k] = bf16(w[k][n])   (LDS-tiled transpose, 32x32)
// ---------------------------------------------------------------------------
__global__ void __launch_bounds__(256) cvt_wT_kernel(
    const float* __restrict__ w, u16* __restrict__ wT)
{
    __shared__ float tile[32][33];
    const int n0 = blockIdx.x * 32;   // N
    const int k0 = blockIdx.y * 32;   // K
    const int tx = threadIdx.x & 31;
    const int ty = threadIdx.x >> 5;  // 0..7
#pragma unroll
    for (int i = 0; i < 4; ++i) {
        int kk = ty + i * 8;
        tile[kk][tx] = w[(k0 + kk) * N_DIM + n0 + tx];
    }
    __syncthreads();
#pragma unroll
    for (int i = 0; i < 4; ++i) {
        int nn = ty + i * 8;
        wT[(int64_t)(n0 + nn) * K_DIM + k0 + tx] = f2bf(tile[tx][nn]);
    }
}

// ---------------------------------------------------------------------------
// Kernel 3: GEMM res = x @ w. 256x256 tile, BK=64, 8 waves (2M x 4N, 128x64
//   output per wave). LDS-traffic-bound fix: only A staged via LDS (64 KiB,
//   2-buf, pair-packed XOR swizzle, 4 global_load_lds/tile); B fragments
//   loaded STRAIGHT from global (L2/L3-resident wT, 16B/lane = 16 full 64B
//   lines per wave-load) into a register double-buffer one K-tile ahead.
//   ONE barrier per K-tile (A ping-pong publish: vmcnt(8) retires the 4 A
//   DMAs; B is pure-register, compiler auto-waits). Per-CU per K-tile:
//   LDS 160KB ~1250-1880cy, L2 64KB ~1090cy, MFMA 2487cy -> MFMA-bound.
// ---------------------------------------------------------------------------
__device__ __forceinline__ void gload_lds16(const void* g, void* l) {
    __builtin_amdgcn_global_load_lds(
        (const __attribute__((address_space(1))) void*)g,
        (__attribute__((address_space(3))) void*)l, 16, 0, 0);
}

#define BAR    __builtin_amdgcn_s_barrier()
#define FENCE  asm volatile("" ::: "memory")
#define VMCNT8 asm volatile("s_waitcnt vmcnt(8)" ::: "memory")

__global__ void __launch_bounds__(512, 2) gemm_kernel(
    const u16* __restrict__ A, const u16* __restrict__ Bt,
    u16* __restrict__ C)
{
    __shared__ u16 sm[2][16384];   // 2 bufs x 32 KiB (A tile 256 rows x 64 k)

    const int tid  = threadIdx.x;
    const int lane = tid & 63;
    const int wave = tid >> 6;

    // T1: XCD-aware bijective swizzle (nwg=640, 640%8==0)
    int bid = blockIdx.x;
    int swz = (bid & 7) * 80 + (bid >> 3);
    const int bm = (swz / 10) * 256;
    const int bn = (swz % 10) * 256;

    const int wm = (wave >> 2) * 128;   // 2 waves in M
    const int wn = (wave & 3) * 64;     // 4 waves in N

    // ---- A LDS read addressing (pair-packed XOR swizzle; verified 0-conflict)
    const int l15 = lane & 15, cq = lane >> 4;
    const int s   = (((l15 & 1) << 2) | cq) ^ ((l15 >> 1) & 7);
    const int rdA = ((wm >> 1) + (l15 >> 1)) * 64 + s * 8;  // + mi*512 + ks*8192 (u16)

    // ---- A staging: 4 gload_lds/tile; chunk ci=(wave*2+j)*64+lane ----
    const int lineJ0 = (wave * 2 + 0) * 8 + (lane >> 3);
    const int lineJ1 = (wave * 2 + 1) * 8 + (lane >> 3);
    const int rc0 = (lane & 7) ^ (lineJ0 & 7);
    const int rc1 = (lane & 7) ^ (lineJ1 & 7);
    const int srow0 = lineJ0 * 2 + (rc0 >> 2), sc0 = (rc0 & 3) * 8;
    const int srow1 = lineJ1 * 2 + (rc1 >> 2), sc1 = (rc1 & 3) * 8;
    const u16* gA0 = A + (int64_t)(bm + srow0) * K_DIM + sc0;
    const u16* gA1 = A + (int64_t)(bm + srow1) * K_DIM + sc1;
    char* ldA0 = (char*)&sm[0][0] + (wave * 2 + 0) * 1024 + lane * 16;
    char* ldA1 = (char*)&sm[0][0] + (wave * 2 + 1) * 1024 + lane * 16;

#define STAGE(KT, BUF) do {                                                \
        gload_lds16(gA0 + (KT),      ldA0 + (BUF) * 32768);                \
        gload_lds16(gA1 + (KT),      ldA1 + (BUF) * 32768);                \
        gload_lds16(gA0 + (KT) + 32, ldA0 + (BUF) * 32768 + 16384);        \
        gload_lds16(gA1 + (KT) + 32, ldA1 + (BUF) * 32768 + 16384);        \
    } while (0)

    // ---- B fragment global base: lane reads 16B of row (bn+wn+n*16+l15) ----
    const u16* gBf = Bt + (int64_t)(bn + wn + l15) * K_DIM + cq * 8;

#define LOADB(BB, KT) do {                                                 \
        _Pragma("unroll")                                                  \
        for (int ks = 0; ks < 2; ++ks) {                                   \
            _Pragma("unroll")                                              \
            for (int n = 0; n < 4; ++n)                                    \
                BB[ks * 4 + n] = *(const bf16x8*)(gBf +                    \
                    n * (16 * K_DIM) + (KT) + ks * 32);                    \
        }                                                                  \
    } while (0)

    f32x4 acc[8][4];
#pragma unroll
    for (int i = 0; i < 8; ++i)
#pragma unroll
        for (int j = 0; j < 4; ++j) acc[i][j] = (f32x4)(0.0f);

    bf16x8 bb0[8], bb1[8];

#define MFMA16(MB, BB, KS) do {                                            \
        __builtin_amdgcn_s_setprio(1);                                     \
        _Pragma("unroll")                                                  \
        for (int mi = 0; mi < 4; ++mi) { _Pragma("unroll")                 \
            for (int n = 0; n < 4; ++n)                                    \
                acc[(MB) + mi][n] = __builtin_amdgcn_mfma_f32_16x16x32_bf16( \
                    af[mi], BB[(KS) * 4 + n], acc[(MB) + mi][n], 0, 0, 0); } \
        __builtin_amdgcn_s_setprio(0);                                     \
    } while (0)

#define COMPUTE(BUF, BB) do {                                              \
        _Pragma("unroll")                                                  \
        for (int ks = 0; ks < 2; ++ks) {                                   \
            const u16* ab = &sm[BUF][0] + ks * 8192 + rdA;                 \
            bf16x8 af[4];                                                  \
            _Pragma("unroll")                                              \
            for (int mi = 0; mi < 4; ++mi)                                 \
                af[mi] = *(const bf16x8*)(ab + mi * 512);                  \
            MFMA16(0, BB, ks);                                             \
            _Pragma("unroll")                                              \
            for (int mi = 0; mi < 4; ++mi)                                 \
                af[mi] = *(const bf16x8*)(ab + (4 + mi) * 512);            \
            MFMA16(4, BB, ks);                                             \
        }                                                                  \
    } while (0)

    // prologue: A(t0) -> buf0, B(t0) -> bb0
    STAGE(0, 0);
    LOADB(bb0, 0);
    VMCNT8;          // 12 outstanding (4 A-DMA + 8 B); oldest 4 = A-DMA done
    BAR; FENCE;

    for (int t2 = 0; t2 < NT; t2 += 2) {
        // tile t2 (buf0, bb0); prefetch t2+1 -> buf1, bb1
        {
            const int ktn = (t2 + 1) * 64;              // t2+1 <= 23: in range
            STAGE(ktn, 1);
            LOADB(bb1, ktn);
            COMPUTE(0, bb0);
            VMCNT8; BAR; FENCE;
        }
        // tile t2+1 (buf1, bb1); prefetch t2+2 -> buf0, bb0
        {
            const int ktn = (t2 + 2 == NT) ? 0 : (t2 + 2) * 64;  // wrap: uniform
            STAGE(ktn, 0);
            LOADB(bb0, ktn);
            COMPUTE(1, bb1);
            VMCNT8; BAR; FENCE;
        }
    }

    // epilogue: C/D layout col=lane&15, row=(lane>>4)*4+r  [m89-verified]
    const int ecol = lane & 15;
    const int erow = (lane >> 4) * 4;
#pragma unroll
    for (int m = 0; m < 8; ++m)
#pragma unroll
        for (int n = 0; n < 4; ++n)
#pragma unroll
            for (int r = 0; r < 4; ++r) {
                int grow = bm + wm + m * 16 + erow + r;
                int gcol = bn + wn + n * 16 + ecol;
                C[(int64_t)grow * N_DIM + gcol] = f2bf(acc[m][n][r]);
            }
}

// ---------------------------------------------------------------------------
// Kernel 4: per-row LayerNorm (per gate over U=512) + LSTM pointwise
//   one WAVE per batch row; 16B/lane loads, butterfly shuffle reduce,
//   fast-exp activations (overflow-safe), float4 stores.
// ---------------------------------------------------------------------------
__device__ __forceinline__ float fsig(float x) {
    return 1.0f / (1.0f + __expf(-x));
}
__device__ __forceinline__ float ftanh(float x) {
    float e = __expf(-2.0f * fabsf(x));
    float r = (1.0f - e) / (1.0f + e);
    return copysignf(r, x);
}

__global__ void __launch_bounds__(256) ln_pointwise_kernel(
    const u16*  __restrict__ res,  const float* __restrict__ bias,
    const float* __restrict__ c1,  const float* __restrict__ c2,
    const float* __restrict__ nw,  const float* __restrict__ nb,
    float* __restrict__ out)
{
    const int wave = threadIdx.x >> 6;
    const int lane = threadIdx.x & 63;
    const int b    = blockIdx.x * 4 + wave;
    const u16* row = res + (int64_t)b * N_DIM;
    const int u0 = lane * 8;

    float v[5][8];
    float rstd[5], mean[5];

#pragma unroll
    for (int g = 0; g < 5; ++g) {
        u16x8 raw = *(const u16x8*)(row + g * 512 + u0);
        const float4* bp = (const float4*)(bias + g * 512 + u0);
        float4 b0 = bp[0], b1 = bp[1];
        v[g][0] = bf2f(raw[0]) + b0.x;  v[g][1] = bf2f(raw[1]) + b0.y;
        v[g][2] = bf2f(raw[2]) + b0.z;  v[g][3] = bf2f(raw[3]) + b0.w;
        v[g][4] = bf2f(raw[4]) + b1.x;  v[g][5] = bf2f(raw[5]) + b1.y;
        v[g][6] = bf2f(raw[6]) + b1.z;  v[g][7] = bf2f(raw[7]) + b1.w;
        float ss = 0.f, q = 0.f;
#pragma unroll
        for (int j = 0; j < 8; ++j) { ss += v[g][j]; q += v[g][j] * v[g][j]; }
#pragma unroll
        for (int off = 1; off < 64; off <<= 1) {
            ss += __shfl_xor(ss, off);
            q  += __shfl_xor(q, off);
        }
        float m   = ss * (1.0f / 512.0f);
        float var = q * (1.0f / 512.0f) - m * m;
        mean[g] = m;
        rstd[g] = rsqrtf(var + 1e-5f);
    }

#pragma unroll
    for (int g = 0; g < 5; ++g) {
        const float4* wp = (const float4*)(nw + g * 512 + u0);
        const float4* bp = (const float4*)(nb + g * 512 + u0);
        float4 w0 = wp[0], w1 = wp[1], n0 = bp[0], n1 = bp[1];
        float ws[8] = {w0.x, w0.y, w0.z, w0.w, w1.x, w1.y, w1.z, w1.w};
        float ns[8] = {n0.x, n0.y, n0.z, n0.w, n1.x, n1.y, n1.z, n1.w};
#pragma unroll
        for (int j = 0; j < 8; ++j)
            v[g][j] = (v[g][j] - mean[g]) * rstd[g] * ws[j] + ns[j];
    }

    const float4* c1p = (const float4*)(c1 + (int64_t)b * 512 + u0);
    const float4* c2p = (const float4*)(c2 + (int64_t)b * 512 + u0);
    float4 c1a = c1p[0], c1b = c1p[1], c2a = c2p[0], c2b = c2p[1];
    float c1s[8] = {c1a.x, c1a.y, c1a.z, c1a.w, c1b.x, c1b.y, c1b.z, c1b.w};
    float c2s[8] = {c2a.x, c2a.y, c2a.z, c2a.w, c2b.x, c2b.y, c2b.z, c2b.w};

    float oc[8], oh[8];
#pragma unroll
    for (int j = 0; j < 8; ++j) {
        float ig  = fsig(v[0][j]);
        float jg  = ftanh(v[1][j]);
        float fg  = fsig(v[2][j]);
        float f2g = fsig(v[3][j]);
        float og  = fsig(v[4][j]);
        float cc  = c1s[j] * fg + c2s[j] * f2g + ig * jg;
        oc[j] = cc;
        oh[j] = cc * og;
    }

    float* oC = out + (int64_t)b * 512 + u0;
    float* oH = out + (int64_t)B_DIM * U_DIM + (int64_t)b * 512 + u0;
    ((float4*)oC)[0] = make_float4(oc[0], oc[1], oc[2], oc[3]);
    ((float4*)oC)[1] = make_float4(oc[4], oc[5], oc[6], oc[7]);
    ((float4*)oH)[0] = make_float4(oh[0], oh[1], oh[2], oh[3]);
    ((float4*)oH)[1] = make_float4(oh[4], oh[5], oh[6], oh[7]);
}

// ---------------------------------------------------------------------------
extern "C" void kernel_launch(void* const* d_in, const int* in_sizes, int n_in,
                              void* d_out, int out_size, void* d_ws, size_t ws_size,
                              hipStream_t stream)
{
    const float* inputs = (const float*)d_in[0];
    const float* c1     = (const float*)d_in[1];
    const float* h1     = (const float*)d_in[2];
    const float* c2     = (const float*)d_in[3];
    const float* h2     = (const float*)d_in[4];
    const float* w      = (const float*)d_in[5];
    const float* bias   = (const float*)d_in[6];
    const float* nw     = (const float*)d_in[7];
    const float* nb     = (const float*)d_in[8];
    float* out = (float*)d_out;

    const size_t XB_BYTES = (size_t)B_DIM * K_DIM * 2;   // 50331648
    const size_t WT_BYTES = (size_t)N_DIM * K_DIM * 2;   // 7864320
    u16* xb  = (u16*)d_ws;
    u16* wT  = (u16*)((char*)d_ws + XB_BYTES);
    u16* res = (u16*)((char*)d_ws + XB_BYTES + WT_BYTES);

    cvt_x_kernel<<<(B_DIM * K_DIM / 4 + 255) / 256, 256, 0, stream>>>(inputs, h1, h2, xb);
    cvt_wT_kernel<<<dim3(N_DIM / 32, K_DIM / 32), 256, 0, stream>>>(w, wT);
    gemm_kernel<<<(B_DIM / 256) * (N_DIM / 256), 512, 0, stream>>>(xb, wT, res);
    ln_pointwise_kernel<<<B_DIM / 4, 256, 0, stream>>>(res, bias, c1, c2, nw, nb, out);
}